// Round 1
// baseline (847.654 us; speedup 1.0000x reference)
//
#include <hip/hip_runtime.h>
#include <hip/hip_bf16.h>

typedef unsigned short u16;
typedef __attribute__((ext_vector_type(8))) short bf16x8;
typedef __attribute__((ext_vector_type(4))) float f32x4;

#define NE 500000
#define NBLOCKS ((NE + 127) / 128)

// ---------------- d_ws layout ----------------
// ushort indices for bf16 transposed weights [N][K]
#define WE0_U 0u        // [128][256]
#define WE1_U 32768u    // [128][128]
#define WE2_U 49152u    // [128][128]
#define WE3_U 65536u    // [16][128]  (rows 10..15 zero)
#define WD0_U 67584u    // [128][32]  (k 5..31 zero)
#define WD1_U 71680u    // [128][128]
#define WD2_U 88064u    // [128][128]
#define WD3_U 104448u   // [256][128]
#define WEND_U 137216u  // byte 274432
// float index base for biases (byte 274432 / 4)
#define BIAS_F 68608u
#define BE0_F 0
#define BE1_F 128
#define BE2_F 256
#define BE3_F 384       // 16 (10 valid, rest 0)
#define BD0_F 400
#define BD1_F 528
#define BD2_F 656
#define BD3_F 784       // 256
#define NBIAS 1040
#define ACC_BYTE 278592u  // double[2]: rl_sum, kl_sum

__device__ __forceinline__ u16 f2bf(float f) {
  __hip_bfloat16 h = __float2bfloat16(f);
  u16 u;
  __builtin_memcpy(&u, &h, 2);
  return u;
}

// ---------------- prep: transpose weights to bf16 [N][K], copy biases, zero accum ----------------
__global__ void prep_kernel(const float* __restrict__ eW0, const float* __restrict__ eb0,
                            const float* __restrict__ eW1, const float* __restrict__ eb1,
                            const float* __restrict__ eW2, const float* __restrict__ eb2,
                            const float* __restrict__ eW3, const float* __restrict__ eb3,
                            const float* __restrict__ dW0, const float* __restrict__ db0,
                            const float* __restrict__ dW1, const float* __restrict__ db1,
                            const float* __restrict__ dW2, const float* __restrict__ db2,
                            const float* __restrict__ dW3, const float* __restrict__ db3,
                            u16* __restrict__ wsu) {
  int t = blockIdx.x * 256 + threadIdx.x;
  float* wsf = (float*)wsu;
  if (t < 32768) {                       // Wt_e0 [128][256]
    int n = t >> 8, k = t & 255;
    wsu[WE0_U + n * 256 + k] = f2bf(eW0[k * 128 + n]);
  } else if (t < 49152) {                // Wt_e1
    int i = t - 32768, n = i >> 7, k = i & 127;
    wsu[WE1_U + n * 128 + k] = f2bf(eW1[k * 128 + n]);
  } else if (t < 65536) {                // Wt_e2
    int i = t - 49152, n = i >> 7, k = i & 127;
    wsu[WE2_U + n * 128 + k] = f2bf(eW2[k * 128 + n]);
  } else if (t < 67584) {                // Wt_e3 [16][128], pad N 10..15
    int i = t - 65536, n = i >> 7, k = i & 127;
    wsu[WE3_U + n * 128 + k] = f2bf(n < 10 ? eW3[k * 10 + n] : 0.f);
  } else if (t < 71680) {                // Wt_d0 [128][32], pad K 5..31
    int i = t - 67584, n = i >> 5, k = i & 31;
    wsu[WD0_U + n * 32 + k] = f2bf(k < 5 ? dW0[k * 128 + n] : 0.f);
  } else if (t < 88064) {                // Wt_d1
    int i = t - 71680, n = i >> 7, k = i & 127;
    wsu[WD1_U + n * 128 + k] = f2bf(dW1[k * 128 + n]);
  } else if (t < 104448) {               // Wt_d2
    int i = t - 88064, n = i >> 7, k = i & 127;
    wsu[WD2_U + n * 128 + k] = f2bf(dW2[k * 128 + n]);
  } else if (t < 137216) {               // Wt_d3 [256][128]
    int i = t - 104448, n = i >> 7, k = i & 127;
    wsu[WD3_U + n * 128 + k] = f2bf(dW3[k * 256 + n]);
  } else if (t < 137216 + NBIAS) {       // biases (fp32)
    int i = t - 137216;
    float v;
    if (i < 128) v = eb0[i];
    else if (i < 256) v = eb1[i - 128];
    else if (i < 384) v = eb2[i - 256];
    else if (i < 400) v = (i - 384 < 10) ? eb3[i - 384] : 0.f;
    else if (i < 528) v = db0[i - 400];
    else if (i < 656) v = db1[i - 528];
    else if (i < 784) v = db2[i - 656];
    else v = db3[i - 784];
    wsf[BIAS_F + i] = v;
  } else if (t < 137216 + NBIAS + 2) {   // zero double accumulators
    ((double*)((char*)wsu + ACC_BYTE))[t - 137216 - NBIAS] = 0.0;
  }
}

// ---------------- fused VAE kernel helpers ----------------
// LDS activation tiles are [128 rows][128 bf16 cols], XOR-swizzled:
// byte ^= (row&7)<<4  (spreads 16 same-col rows over 8x16B slots -> 2-way max)
__device__ __forceinline__ bf16x8 ldA(const u16* buf, int row, int k) {
  int byte = (row * 256 + k * 2) ^ ((row & 7) << 4);
  return *(const bf16x8*)((const char*)buf + byte);
}

__device__ __forceinline__ void init_acc(f32x4 acc[2][8], const float* __restrict__ bias, int j) {
  #pragma unroll
  for (int n = 0; n < 8; ++n) {
    float b = bias[n * 16 + j];
    f32x4 v = {b, b, b, b};
    acc[0][n] = v;
    acc[1][n] = v;
  }
}

// K=128 GEMM accumulate: in LDS [128][128] -> acc (wave computes 32 rows x 128 cols)
template<int LDW>
__device__ __forceinline__ void gemm_acc(const u16* __restrict__ inb, const u16* __restrict__ Wt,
                                         int k0, f32x4 acc[2][8], int rw, int g, int j) {
  #pragma unroll
  for (int kk = 0; kk < 4; ++kk) {
    int k = kk * 32 + g * 8;
    bf16x8 a0 = ldA(inb, rw + j, k);
    bf16x8 a1 = ldA(inb, rw + 16 + j, k);
    #pragma unroll
    for (int n = 0; n < 8; ++n) {
      bf16x8 b = *(const bf16x8*)(Wt + (n * 16 + j) * LDW + k0 + k);
      acc[0][n] = __builtin_amdgcn_mfma_f32_16x16x32_bf16(a0, b, acc[0][n], 0, 0, 0);
      acc[1][n] = __builtin_amdgcn_mfma_f32_16x16x32_bf16(a1, b, acc[1][n], 0, 0, 0);
    }
  }
}

// C layout (verified): col = lane&15, row = (lane>>4)*4 + reg
__device__ __forceinline__ void store_act(const f32x4 acc[2][8], u16* outb, int rw, int g, int j,
                                          bool relu) {
  #pragma unroll
  for (int m = 0; m < 2; ++m)
    #pragma unroll
    for (int n = 0; n < 8; ++n)
      #pragma unroll
      for (int r = 0; r < 4; ++r) {
        float v = acc[m][n][r];
        if (relu) v = fmaxf(v, 0.f);
        int row = rw + m * 16 + g * 4 + r;
        int c = n * 16 + j;
        int byte = (row * 256 + c * 2) ^ ((row & 7) << 4);
        *(u16*)((char*)outb + byte) = f2bf(v);
      }
}

// gather 128 node-feature rows (fp32) -> bf16 swizzled LDS tile
__device__ __forceinline__ void stage(const float* __restrict__ x, const int* __restrict__ idx,
                                      int e0, u16* buf, int tid) {
  int gg = tid >> 4;   // 0..15 : row group
  int jj = tid & 15;   // 0..15 : 8-float chunk within row
  #pragma unroll
  for (int p = 0; p < 8; ++p) {
    int rl = p * 16 + gg;
    int e = e0 + rl;
    if (e >= NE) e = NE - 1;
    int node = idx[e];
    const f32x4* src = (const f32x4*)(x + (size_t)node * 128 + jj * 8);
    f32x4 v0 = src[0];
    f32x4 v1 = src[1];
    bf16x8 o;
    o[0] = (short)f2bf(v0[0]); o[1] = (short)f2bf(v0[1]);
    o[2] = (short)f2bf(v0[2]); o[3] = (short)f2bf(v0[3]);
    o[4] = (short)f2bf(v1[0]); o[5] = (short)f2bf(v1[1]);
    o[6] = (short)f2bf(v1[2]); o[7] = (short)f2bf(v1[3]);
    int byte = (rl * 256 + jj * 16) ^ ((rl & 7) << 4);
    *(bf16x8*)((char*)buf + byte) = o;
  }
}

// ---------------- main fused kernel: 1 block = 128 edges, 4 waves x 32 rows ----------------
__global__ __launch_bounds__(256, 2) void vae_kernel(
    const float* __restrict__ x, const int* __restrict__ rowi, const int* __restrict__ coli,
    const float* __restrict__ eps, const u16* __restrict__ wsu, double* __restrict__ accg,
    float* __restrict__ out) {
  __shared__ __align__(16) u16 bufA[128 * 128];
  __shared__ __align__(16) u16 bufB[128 * 128];
  __shared__ __align__(16) u16 zbuf[128 * 32];   // [row][32], k 5..31 zero, no swizzle
  __shared__ float redr[4], redk[4];

  const float* wsf = (const float*)wsu;
  const int tid = threadIdx.x;
  const int lane = tid & 63;
  const int wave = tid >> 6;
  const int g = lane >> 4;
  const int j = lane & 15;
  const int rw = wave * 32;
  const int e0 = blockIdx.x * 128;

  for (int i = tid; i < 128 * 32; i += 256) zbuf[i] = 0;

  float kl_part = 0.f, rl_part = 0.f;
  f32x4 acc[2][8];

  // ---- enc0: pair[128x256] @ eW0 -> h (K split over two staged halves) ----
  stage(x, rowi, e0, bufA, tid);
  __syncthreads();
  init_acc(acc, wsf + BIAS_F + BE0_F, j);
  gemm_acc<256>(bufA, wsu + WE0_U, 0, acc, rw, g, j);
  __syncthreads();
  stage(x, coli, e0, bufA, tid);
  __syncthreads();
  gemm_acc<256>(bufA, wsu + WE0_U, 128, acc, rw, g, j);
  store_act(acc, bufB, rw, g, j, true);
  __syncthreads();

  // ---- enc1: bufB -> bufA ----
  init_acc(acc, wsf + BIAS_F + BE1_F, j);
  gemm_acc<128>(bufB, wsu + WE1_U, 0, acc, rw, g, j);
  store_act(acc, bufA, rw, g, j, true);
  __syncthreads();

  // ---- enc2: bufA -> bufB ----
  init_acc(acc, wsf + BIAS_F + BE2_F, j);
  gemm_acc<128>(bufA, wsu + WE2_U, 0, acc, rw, g, j);
  store_act(acc, bufB, rw, g, j, true);
  __syncthreads();

  // ---- enc3: bufB -> mu/logvar fragments (N=16, cols 0..4 mu, 5..9 logvar) ----
  f32x4 a3[2];
  {
    float b3 = wsf[BIAS_F + BE3_F + j];
    f32x4 v = {b3, b3, b3, b3};
    a3[0] = v;
    a3[1] = v;
    #pragma unroll
    for (int kk = 0; kk < 4; ++kk) {
      int k = kk * 32 + g * 8;
      bf16x8 q0 = ldA(bufB, rw + j, k);
      bf16x8 q1 = ldA(bufB, rw + 16 + j, k);
      bf16x8 b = *(const bf16x8*)(wsu + WE3_U + j * 128 + k);
      a3[0] = __builtin_amdgcn_mfma_f32_16x16x32_bf16(q0, b, a3[0], 0, 0, 0);
      a3[1] = __builtin_amdgcn_mfma_f32_16x16x32_bf16(q1, b, a3[1], 0, 0, 0);
    }
  }

  // ---- reparameterization + KL (lanes with col j<5 own latent dim j) ----
  {
    int src = g * 16 + ((j + 5) & 15);  // same rows (same g), col j+5 = logvar
    #pragma unroll
    for (int m = 0; m < 2; ++m)
      #pragma unroll
      for (int r = 0; r < 4; ++r) {
        float muv = a3[m][r];
        float lvv = __shfl(a3[m][r], src, 64);
        if (j < 5) {
          int row = rw + m * 16 + g * 4 + r;
          int e = e0 + row;
          int ec = e < NE ? e : NE - 1;
          float stdv = __expf(0.5f * lvv);
          float zv = muv + eps[(size_t)ec * 5 + j] * stdv;
          zbuf[row * 32 + j] = f2bf(zv);
          if (e < NE) kl_part += 1.0f + lvv - muv * muv - __expf(lvv);
        }
      }
  }
  __syncthreads();

  // ---- dec0: z[128x5 padded 32] @ dW0 -> bufA ----
  init_acc(acc, wsf + BIAS_F + BD0_F, j);
  {
    int k = g * 8;
    bf16x8 q0 = *(const bf16x8*)(zbuf + (rw + j) * 32 + k);
    bf16x8 q1 = *(const bf16x8*)(zbuf + (rw + 16 + j) * 32 + k);
    #pragma unroll
    for (int n = 0; n < 8; ++n) {
      bf16x8 b = *(const bf16x8*)(wsu + WD0_U + (n * 16 + j) * 32 + k);
      acc[0][n] = __builtin_amdgcn_mfma_f32_16x16x32_bf16(q0, b, acc[0][n], 0, 0, 0);
      acc[1][n] = __builtin_amdgcn_mfma_f32_16x16x32_bf16(q1, b, acc[1][n], 0, 0, 0);
    }
  }
  store_act(acc, bufA, rw, g, j, true);
  __syncthreads();

  // ---- dec1: bufA -> bufB ----
  init_acc(acc, wsf + BIAS_F + BD1_F, j);
  gemm_acc<128>(bufA, wsu + WD1_U, 0, acc, rw, g, j);
  store_act(acc, bufB, rw, g, j, true);
  __syncthreads();

  // ---- dec2: bufB -> bufA ----
  init_acc(acc, wsf + BIAS_F + BD2_F, j);
  gemm_acc<128>(bufB, wsu + WD2_U, 0, acc, rw, g, j);
  store_act(acc, bufA, rw, g, j, true);
  __syncthreads();

  // ---- dec3 (N=256 in two halves) fused with recon loss ----
  int rn[2][4], cn[2][4];
  #pragma unroll
  for (int m = 0; m < 2; ++m)
    #pragma unroll
    for (int r = 0; r < 4; ++r) {
      int e = e0 + rw + m * 16 + g * 4 + r;
      int ec = e < NE ? e : NE - 1;
      rn[m][r] = rowi[ec];
      cn[m][r] = coli[ec];
    }
  float rlsq[2][4] = {{0.f, 0.f, 0.f, 0.f}, {0.f, 0.f, 0.f, 0.f}};
  #pragma unroll
  for (int nh = 0; nh < 2; ++nh) {
    init_acc(acc, wsf + BIAS_F + BD3_F + nh * 128, j);
    #pragma unroll
    for (int kk = 0; kk < 4; ++kk) {
      int k = kk * 32 + g * 8;
      bf16x8 q0 = ldA(bufA, rw + j, k);
      bf16x8 q1 = ldA(bufA, rw + 16 + j, k);
      #pragma unroll
      for (int n = 0; n < 8; ++n) {
        bf16x8 b = *(const bf16x8*)(wsu + WD3_U + (nh * 128 + n * 16 + j) * 128 + k);
        acc[0][n] = __builtin_amdgcn_mfma_f32_16x16x32_bf16(q0, b, acc[0][n], 0, 0, 0);
        acc[1][n] = __builtin_amdgcn_mfma_f32_16x16x32_bf16(q1, b, acc[1][n], 0, 0, 0);
      }
    }
    #pragma unroll
    for (int m = 0; m < 2; ++m)
      #pragma unroll
      for (int n = 0; n < 8; ++n)
        #pragma unroll
        for (int r = 0; r < 4; ++r) {
          int c = nh * 128 + n * 16 + j;
          int node = (c < 128) ? rn[m][r] : cn[m][r];
          float pv = x[(size_t)node * 128 + (c & 127)];
          float d = acc[m][n][r] - pv;
          rlsq[m][r] += d * d;
        }
  }

  // per-row reduce over 16 lanes (cols) -> rl, affinity
  #pragma unroll
  for (int m = 0; m < 2; ++m)
    #pragma unroll
    for (int r = 0; r < 4; ++r) {
      float v = rlsq[m][r];
      v += __shfl_xor(v, 1);
      v += __shfl_xor(v, 2);
      v += __shfl_xor(v, 4);
      v += __shfl_xor(v, 8);
      if (j == 0) {
        int e = e0 + rw + m * 16 + g * 4 + r;
        if (e < NE) {
          float rl = sqrtf(v);
          out[e] = 1.0f / (1.0f + 3.5f * rl);
          rl_part += rl;
        }
      }
    }

  // ---- block reduction + global double atomics ----
  float kv = kl_part, rv = rl_part;
  #pragma unroll
  for (int msk = 1; msk < 64; msk <<= 1) {
    kv += __shfl_xor(kv, msk);
    rv += __shfl_xor(rv, msk);
  }
  if (lane == 0) {
    redk[wave] = kv;
    redr[wave] = rv;
  }
  __syncthreads();
  if (tid == 0) {
    atomicAdd(&accg[0], (double)(redr[0] + redr[1] + redr[2] + redr[3]));
    atomicAdd(&accg[1], (double)(redk[0] + redk[1] + redk[2] + redk[3]));
  }
}

// ---------------- finalize the two scalar means ----------------
__global__ void fin_kernel(const double* __restrict__ accg, float* __restrict__ out) {
  if (threadIdx.x == 0) {
    out[NE] = (float)(accg[0] / (double)NE);
    // kl_mean = -0.5*BETA * sum(1+lv-mu^2-exp(lv)) / (E*L),  BETA=10, L=5
    out[NE + 1] = (float)(accg[1] * (-0.5 * 10.0 / ((double)NE * 5.0)));
  }
}

extern "C" void kernel_launch(void* const* d_in, const int* in_sizes, int n_in,
                              void* d_out, int out_size, void* d_ws, size_t ws_size,
                              hipStream_t stream) {
  (void)in_sizes; (void)n_in; (void)out_size; (void)ws_size;
  const float* x   = (const float*)d_in[0];
  const int*   row = (const int*)d_in[1];
  const int*   col = (const int*)d_in[2];
  const float* eps = (const float*)d_in[3];
  u16* wsu = (u16*)d_ws;
  double* accg = (double*)((char*)d_ws + ACC_BYTE);
  float* out = (float*)d_out;

  prep_kernel<<<541, 256, 0, stream>>>(
      (const float*)d_in[4],  (const float*)d_in[5],  (const float*)d_in[6],  (const float*)d_in[7],
      (const float*)d_in[8],  (const float*)d_in[9],  (const float*)d_in[10], (const float*)d_in[11],
      (const float*)d_in[12], (const float*)d_in[13], (const float*)d_in[14], (const float*)d_in[15],
      (const float*)d_in[16], (const float*)d_in[17], (const float*)d_in[18], (const float*)d_in[19],
      wsu);
  vae_kernel<<<NBLOCKS, 256, 0, stream>>>(x, row, col, eps, wsu, accg, out);
  fin_kernel<<<1, 64, 0, stream>>>(accg, out);
}